// Round 18
// baseline (100.340 us; speedup 1.0000x reference)
//
#include <hip/hip_runtime.h>

typedef unsigned short u16;
typedef short bf16x8 __attribute__((ext_vector_type(8)));
typedef float f32x4 __attribute__((ext_vector_type(4)));

#define BATCH 2
#define SEQ   2048
#define CH    1024
#define NHEAD 16
#define HDIM  64
#define ROWS  (BATCH*SEQ)   // 4096

#define WAITV(N) asm volatile("s_waitcnt vmcnt(" #N ")" ::: "memory")

__device__ __forceinline__ u16 f2b(float f) {
  unsigned u = __builtin_bit_cast(unsigned, f);
  u += 0x7FFFu + ((u >> 16) & 1u);
  return (u16)(u >> 16);
}
__device__ __forceinline__ float b2f(u16 h) {
  unsigned u = ((unsigned)h) << 16;
  return __builtin_bit_cast(float, u);
}
__device__ __forceinline__ float exp2_fast(float x) {
  float r; asm("v_exp_f32 %0, %1" : "=v"(r) : "v"(x)); return r;
}
__device__ __forceinline__ unsigned cvt_pk_bf16(float a, float b) {
  unsigned r; asm("v_cvt_pk_bf16_f32 %0, %1, %2" : "=v"(r) : "v"(a), "v"(b)); return r;
}

__device__ __forceinline__ void gload_lds16(const void* g, void* l) {
  __builtin_amdgcn_global_load_lds(
      (const __attribute__((address_space(1))) unsigned int*)g,
      (__attribute__((address_space(3))) unsigned int*)l, 16, 0, 0);
}

// ---------- fused prep: x f32->bf16, both weight transposes (one launch) ----
__global__ void csa_prep(const float* __restrict__ x,
                         const float* __restrict__ wa, const float* __restrict__ wp,
                         u16* __restrict__ xb, u16* __restrict__ wat,
                         u16* __restrict__ wpt) {
  __shared__ float tile[32][33];
  const int b = blockIdx.x, t = threadIdx.x;
  if (b < 2048) {               // convert x: 524288 uint4-pairs
    int i = b * 256 + t;
    const float4* f4 = (const float4*)x;
    float4 v0 = f4[2*i], v1 = f4[2*i+1];
    ushort4 o0, o1;
    o0.x = f2b(v0.x); o0.y = f2b(v0.y); o0.z = f2b(v0.z); o0.w = f2b(v0.w);
    o1.x = f2b(v1.x); o1.y = f2b(v1.y); o1.z = f2b(v1.z); o1.w = f2b(v1.w);
    ((ushort4*)xb)[2*i]   = o0;
    ((ushort4*)xb)[2*i+1] = o1;
    return;
  }
  int bb = b - 2048;            // transpose: 4096 blocks (128 x 32)
  int bx = bb & 127, by = bb >> 7;
  const float* in; u16* out; int C;
  if (bx < 96) { in = wa; out = wat; C = 3*CH; }
  else         { in = wp; out = wpt; C = CH; bx -= 96; }
  const int R = CH;
  const int bxc = bx * 32, byc = by * 32;
  const int tx = t & 31, ty = t >> 5;
  #pragma unroll
  for (int j = 0; j < 4; ++j) {
    int r = byc + ty + j*8, c = bxc + tx;
    tile[ty + j*8][tx] = in[(size_t)r*C + c];
  }
  __syncthreads();
  #pragma unroll
  for (int j = 0; j < 4; ++j) {
    int oc = bxc + ty + j*8;
    int orr = byc + tx;
    out[(size_t)oc*R + orr] = f2b(tile[tx][ty + j*8]);
  }
}

// ---------- QKV GEMM: [4096][3072] = xb * wat^T + b -------------------------
// BM=256, BN=192, BK=64; 512 thr = 8 waves (2M x 4N); grid 16x16 = 1/CU.
// Counted-vmcnt pipeline (T4): A triple-buffered (2-iter latency cover),
// B double-buffered; raw s_barrier x2/iter, NO vmcnt(0) drain in main loop.
// T2 XOR swizzle on LDS tiles (read 16-way conflict -> 2-way free).
__global__ __launch_bounds__(512) void csa_gemm_qkv(
    const u16* __restrict__ A, const u16* __restrict__ Bt,
    const float* __restrict__ bias,
    u16* __restrict__ qbo, u16* __restrict__ kb, u16* __restrict__ vtb)
{
  __shared__ __align__(16) u16 As[3][256*64];   // 96 KB
  __shared__ __align__(16) u16 Bs[2][192*64];   // 48 KB
  const int t = threadIdx.x, lane = t & 63, w = t >> 6;
  const int wm = w >> 2, wn = w & 3, g = lane >> 4, qi = lane & 15;
  const int xq = (qi & 7) * 8;

  const int wgid = blockIdx.y * 16 + blockIdx.x;
  const int c8 = wgid & 7, inner = wgid >> 3;
  const int bm = (c8 >> 1) * 4 + (inner >> 3);
  const int bn = (c8 & 1) * 8 + (inner & 7);

  f32x4 acc[8][3] = {};

  const u16* Ab = A  + (size_t)(bm*256)*CH;
  const u16* Bb = Bt + (size_t)(bn*192)*CH;
  const int srow = t >> 3;                               // 0..63
  const int scolsw = ((t & 7) * 8) ^ ((srow & 7) * 8);   // pre-swizzled src col

#define QKV_STAGE_A(kt_, buf_) do { const size_t k_ = (size_t)(kt_)*64;            \
    gload_lds16(Ab + (size_t)(  0 + srow)*CH + k_ + scolsw, &As[buf_][      w*512]); \
    gload_lds16(Ab + (size_t)( 64 + srow)*CH + k_ + scolsw, &As[buf_][ 4096+w*512]); \
    gload_lds16(Ab + (size_t)(128 + srow)*CH + k_ + scolsw, &As[buf_][ 8192+w*512]); \
    gload_lds16(Ab + (size_t)(192 + srow)*CH + k_ + scolsw, &As[buf_][12288+w*512]); \
  } while (0)
#define QKV_STAGE_B(kt_, buf_) do { const size_t k_ = (size_t)(kt_)*64;            \
    gload_lds16(Bb + (size_t)(  0 + srow)*CH + k_ + scolsw, &Bs[buf_][      w*512]); \
    gload_lds16(Bb + (size_t)( 64 + srow)*CH + k_ + scolsw, &Bs[buf_][ 4096+w*512]); \
    gload_lds16(Bb + (size_t)(128 + srow)*CH + k_ + scolsw, &Bs[buf_][ 8192+w*512]); \
  } while (0)

  // prologue (FIFO order matters for vmcnt counting): A(0), B(0), A(1)
  QKV_STAGE_A(0, 0); QKV_STAGE_B(0, 0); QKV_STAGE_A(1, 1);

  int a3 = 0;                                  // kt % 3
  for (int kt = 0; kt < 16; ++kt) {
    if (kt < 15) QKV_STAGE_B(kt + 1, (kt + 1) & 1);
    if (kt < 14) { int ab = a3 + 2; if (ab >= 3) ab -= 3; QKV_STAGE_A(kt + 2, ab); }
    // drain exactly {A(kt), B(kt)}: keep A(kt+1)[4] + B(kt+1)[3] + A(kt+2)[4]
    if (kt < 14)       WAITV(11);
    else if (kt == 14) WAITV(7);
    else               WAITV(0);
    __builtin_amdgcn_s_barrier();              // all waves' tile-kt loads landed
    __builtin_amdgcn_sched_barrier(0);         // pin ds_reads after the barrier
    const u16* Ac = &As[a3][0];
    const u16* Bc = &Bs[kt & 1][0];
    #pragma unroll
    for (int kk = 0; kk < 2; ++kk) {
      bf16x8 af[8], bfr[3];
      #pragma unroll
      for (int m = 0; m < 8; ++m)
        af[m] = *(const bf16x8*)&Ac[(wm*128 + m*16 + qi)*64 + ((kk*32 + g*8) ^ xq)];
      #pragma unroll
      for (int n = 0; n < 3; ++n)
        bfr[n] = *(const bf16x8*)&Bc[(wn*48 + n*16 + qi)*64 + ((kk*32 + g*8) ^ xq)];
      #pragma unroll
      for (int m = 0; m < 8; ++m)
        #pragma unroll
        for (int n = 0; n < 3; ++n)
          acc[m][n] = __builtin_amdgcn_mfma_f32_16x16x32_bf16(af[m], bfr[n], acc[m][n], 0, 0, 0);
    }
    __builtin_amdgcn_s_barrier();              // reads done -> buffers reusable
    a3 = (a3 == 2) ? 0 : a3 + 1;
  }
#undef QKV_STAGE_A
#undef QKV_STAGE_B

  // epilogue: scatter to q/k [bh][t][64] and v^T [bh][64][t]
  #pragma unroll
  for (int m = 0; m < 8; ++m) {
    const int row0 = bm*256 + wm*128 + m*16 + g*4;
    const int bb = row0 >> 11;
    const int t0 = row0 & 2047;
    #pragma unroll
    for (int n = 0; n < 3; ++n) {
      const int col = bn*192 + wn*48 + n*16 + qi;
      const float bv = bias[col];
      const int which = col >> 10;      // 0=q 1=k 2=v
      const int cc = col & 1023;
      const int h = cc >> 6, d = cc & 63;
      const int bh = bb*16 + h;
      if (which == 2) {
        ushort4 pw;
        pw.x = f2b(acc[m][n][0] + bv);
        pw.y = f2b(acc[m][n][1] + bv);
        pw.z = f2b(acc[m][n][2] + bv);
        pw.w = f2b(acc[m][n][3] + bv);
        *(ushort4*)&vtb[((size_t)bh*HDIM + d)*SEQ + t0] = pw;
      } else {
        u16* dst = (which == 0) ? qbo : kb;
        #pragma unroll
        for (int r = 0; r < 4; ++r)
          dst[((size_t)bh*SEQ + t0 + r)*HDIM + d] = f2b(acc[m][n][r] + bv);
      }
    }
  }
}

// ---------- proj GEMM: out[4096][1024] f32 = y * wpt^T + b ------------------
// 128x128 tile, 256 thr (4 waves 2x2); same T4 counted-vmcnt + T2 swizzle.
__global__ __launch_bounds__(256) void csa_gemm_proj(
    const u16* __restrict__ A, const u16* __restrict__ Bt,
    const float* __restrict__ bias, float* __restrict__ out)
{
  __shared__ __align__(16) u16 As[3][128*64];   // 48 KB
  __shared__ __align__(16) u16 Bs[2][128*64];   // 32 KB
  const int t = threadIdx.x, lane = t & 63, w = t >> 6;
  const int wm = w >> 1, wn = w & 1, g = lane >> 4, qi = lane & 15;
  const int xq = (qi & 7) * 8;
  const int bm = blockIdx.y, bn = blockIdx.x;

  f32x4 acc[4][4] = {};

  const u16* Ab = A  + (size_t)(bm*128)*CH;
  const u16* Bb = Bt + (size_t)(bn*128)*CH;
  const int srow = t >> 3;                               // 0..31
  const int scolsw = ((t & 7) * 8) ^ ((srow & 7) * 8);

#define PRJ_STAGE(P_, base_, kt_, buf_) do { const size_t k_ = (size_t)(kt_)*64;      \
    gload_lds16(P_ + (size_t)( 0 + srow)*CH + k_ + scolsw, &base_[buf_][     w*512]); \
    gload_lds16(P_ + (size_t)(32 + srow)*CH + k_ + scolsw, &base_[buf_][2048+w*512]); \
    gload_lds16(P_ + (size_t)(64 + srow)*CH + k_ + scolsw, &base_[buf_][4096+w*512]); \
    gload_lds16(P_ + (size_t)(96 + srow)*CH + k_ + scolsw, &base_[buf_][6144+w*512]); \
  } while (0)

  PRJ_STAGE(Ab, As, 0, 0); PRJ_STAGE(Bb, Bs, 0, 0); PRJ_STAGE(Ab, As, 1, 1);

  int a3 = 0;
  for (int kt = 0; kt < 16; ++kt) {
    if (kt < 15) PRJ_STAGE(Bb, Bs, kt + 1, (kt + 1) & 1);
    if (kt < 14) { int ab = a3 + 2; if (ab >= 3) ab -= 3; PRJ_STAGE(Ab, As, kt + 2, ab); }
    if (kt < 14)       WAITV(12);   // keep A(kt+1)[4]+B(kt+1)[4]+A(kt+2)[4]
    else if (kt == 14) WAITV(8);
    else               WAITV(0);
    __builtin_amdgcn_s_barrier();
    __builtin_amdgcn_sched_barrier(0);
    const u16* Ac = &As[a3][0];
    const u16* Bc = &Bs[kt & 1][0];
    #pragma unroll
    for (int kk = 0; kk < 2; ++kk) {
      bf16x8 af[4], bfr[4];
      #pragma unroll
      for (int m = 0; m < 4; ++m)
        af[m] = *(const bf16x8*)&Ac[(wm*64 + m*16 + qi)*64 + ((kk*32 + g*8) ^ xq)];
      #pragma unroll
      for (int n = 0; n < 4; ++n)
        bfr[n] = *(const bf16x8*)&Bc[(wn*64 + n*16 + qi)*64 + ((kk*32 + g*8) ^ xq)];
      #pragma unroll
      for (int m = 0; m < 4; ++m)
        #pragma unroll
        for (int n = 0; n < 4; ++n)
          acc[m][n] = __builtin_amdgcn_mfma_f32_16x16x32_bf16(af[m], bfr[n], acc[m][n], 0, 0, 0);
    }
    __builtin_amdgcn_s_barrier();
    a3 = (a3 == 2) ? 0 : a3 + 1;
  }
#undef PRJ_STAGE

  #pragma unroll
  for (int m = 0; m < 4; ++m) {
    const int row0 = bm*128 + wm*64 + m*16 + g*4;
    #pragma unroll
    for (int n = 0; n < 4; ++n) {
      const int col = bn*128 + wn*64 + n*16 + qi;
      const float bv = bias[col];
      #pragma unroll
      for (int r = 0; r < 4; ++r)
        out[(size_t)(row0 + r)*CH + col] = acc[m][n][r] + bv;
    }
  }
}

// ---------- causal flash attention v5 + T5 setprio (final) -------------------
// grid 32 x 8, 512 thr (8 waves x 16 q-rows), q-tile 128, pairs {p, 15-p}
// -> uniform 17 kt-iterations per block. Each iteration processes TWO 64-key
// sub-tiles (a/b) from one 128-key staged K/V tile. Double-buffered, single
// barrier per iteration. Swapped QK^T (mfma(K,Q)); per-lane-partial online
// softmax w/ defer-max; in-LDS per-wave P; branchless diagonal masking.
// T5: setprio(1) around the QK and PV MFMA clusters (m191: +4-7% attn when
// waves compete at different phases; zero correctness risk).
__global__ __launch_bounds__(512) void csa_attn(
    const u16* __restrict__ qb, const u16* __restrict__ kb,
    const u16* __restrict__ vtb, u16* __restrict__ yout)
{
  const int bh = blockIdx.x, pair = blockIdx.y;
  const int bidx = bh >> 4, h = bh & 15;
  const int t = threadIdx.x, lane = t & 63, w = t >> 6;   // w 0..7
  const int g = lane >> 4, qi = lane & 15;
  __shared__ __align__(16) u16 Ks[2][128*64];   // 32 KB
  __shared__ __align__(16) u16 Vs[2][64*128];   // 32 KB, V^T [d][key]
  __shared__ __align__(16) u16 Ps[8][2][16*64]; // 32 KB, per-wave P [sub][q][key]

  const size_t kvbase = (size_t)bh * SEQ * HDIM;
  const u16* kb_bh  = kb  + kvbase;
  const u16* vtb_bh = vtb + kvbase;

  const int krow_  = t >> 3;                                  // 0..63
  const int kcolsw = ((t & 7) * 8) ^ ((krow_ & 7) * 8);
  const int vd_    = t >> 4;                                  // 0..31
  const int vcolsw = ((t & 15) * 8) ^ ((vd_ & 15) * 8);

  int offKb[2][4], offVb[2][4], offPw[4], offPr[2];
  #pragma unroll
  for (int c = 0; c < 2; ++c) {
    offPr[c] = qi*64 + ((c*32 + g*8) ^ ((qi & 7) * 8));
    #pragma unroll
    for (int s4 = 0; s4 < 4; ++s4)
      offKb[c][s4] = (s4*16 + qi)*64 + ((c*32 + g*8) ^ ((qi & 7) * 8));
    #pragma unroll
    for (int nf = 0; nf < 4; ++nf)
      offVb[c][nf] = (nf*16 + qi)*128 + ((c*32 + g*8) ^ (qi * 8));
  }
  #pragma unroll
  for (int s4 = 0; s4 < 4; ++s4)
    offPw[s4] = qi*64 + ((s4*16 + g*4) ^ ((qi & 7) * 8));

  const float QSCALE = 0.18033688011112042f;   // 0.125 * log2(e)
  const int lqa = w*16 + qi;

  for (int half = 0; half < 2; ++half) {
    const int qt = half ? (15 - pair) : pair;
    const int qrow = qt*128 + w*16;
    const int ntile = qt + 1;

    bf16x8 qf[2];
    #pragma unroll
    for (int c = 0; c < 2; ++c) {
      qf[c] = *(const bf16x8*)&qb[(kvbase + (size_t)(qrow + qi)*HDIM) + c*32 + g*8];
      #pragma unroll
      for (int e = 0; e < 8; ++e)
        qf[c][e] = (short)f2b(b2f((u16)qf[c][e]) * QSCALE);
    }

    f32x4 yacc[4] = {};
    float mrun = -1e30f, srun = 0.f;

    __syncthreads();
    {
      const u16* kp = kb_bh;
      gload_lds16(kp + (size_t)krow_*64 + kcolsw,        &Ks[0][       w*512]);
      gload_lds16(kp + (size_t)(64 + krow_)*64 + kcolsw, &Ks[0][4096 + w*512]);
      const u16* vp = vtb_bh;
      gload_lds16(vp + (size_t)vd_*SEQ + vcolsw,         &Vs[0][       w*512]);
      gload_lds16(vp + (size_t)(32 + vd_)*SEQ + vcolsw,  &Vs[0][4096 + w*512]);
    }
    __syncthreads();

    int buf = 0;
    for (int kt = 0; kt < ntile; ++kt) {
      if (kt + 1 < ntile) {
        const u16* kp = kb_bh + (size_t)((kt + 1) * 128) * 64;
        gload_lds16(kp + (size_t)krow_*64 + kcolsw,        &Ks[buf^1][       w*512]);
        gload_lds16(kp + (size_t)(64 + krow_)*64 + kcolsw, &Ks[buf^1][4096 + w*512]);
        const u16* vp = vtb_bh + (kt + 1) * 128;
        gload_lds16(vp + (size_t)vd_*SEQ + vcolsw,         &Vs[buf^1][       w*512]);
        gload_lds16(vp + (size_t)(32 + vd_)*SEQ + vcolsw,  &Vs[buf^1][4096 + w*512]);
      }

      f32x4 sa[4] = {}, sb[4] = {};
      __builtin_amdgcn_s_setprio(1);
      #pragma unroll
      for (int c = 0; c < 2; ++c)
        #pragma unroll
        for (int s4 = 0; s4 < 4; ++s4) {
          bf16x8 ka = *(const bf16x8*)&Ks[buf][offKb[c][s4]];
          sa[s4] = __builtin_amdgcn_mfma_f32_16x16x32_bf16(ka, qf[c], sa[s4], 0, 0, 0);
        }
      #pragma unroll
      for (int c = 0; c < 2; ++c)
        #pragma unroll
        for (int s4 = 0; s4 < 4; ++s4) {
          bf16x8 kbv = *(const bf16x8*)&Ks[buf][4096 + offKb[c][s4]];
          sb[s4] = __builtin_amdgcn_mfma_f32_16x16x32_bf16(kbv, qf[c], sb[s4], 0, 0, 0);
        }
      __builtin_amdgcn_s_setprio(0);

      if (kt == ntile - 1) {
        #pragma unroll
        for (int s4 = 0; s4 < 4; ++s4)
          #pragma unroll
          for (int r = 0; r < 4; ++r) {
            const int lk = s4*16 + g*4 + r;
            if (lk > lqa)      sa[s4][r] = -3.0e38f;
            if (lk > lqa - 64) sb[s4][r] = -3.0e38f;
          }
      }

      float tmax = sa[0][0];
      #pragma unroll
      for (int s4 = 0; s4 < 4; ++s4)
        #pragma unroll
        for (int r = 0; r < 4; ++r) {
          tmax = fmaxf(tmax, sa[s4][r]);
          tmax = fmaxf(tmax, sb[s4][r]);
        }
      if (!__all(tmax - mrun <= 11.5f)) {
        float tmf = fmaxf(tmax, __shfl_xor(tmax, 16));
        tmf = fmaxf(tmf, __shfl_xor(tmf, 32));
        float mnew = fmaxf(mrun, tmf);
        float fac = exp2_fast(mrun - mnew);
        #pragma unroll
        for (int r = 0; r < 4; ++r) {
          float fr = __shfl(fac, g*4 + r);
          #pragma unroll
          for (int nf = 0; nf < 4; ++nf) yacc[nf][r] *= fr;
        }
        srun *= fac;
        mrun = mnew;
      }
      float tsum = 0.f;
      #pragma unroll
      for (int s4 = 0; s4 < 4; ++s4)
        #pragma unroll
        for (int r = 0; r < 4; ++r) {
          float pa = exp2_fast(sa[s4][r] - mrun);
          float pb = exp2_fast(sb[s4][r] - mrun);
          sa[s4][r] = pa; sb[s4][r] = pb;
          tsum += pa + pb;
        }
      srun += tsum;

      #pragma unroll
      for (int s4 = 0; s4 < 4; ++s4) {
        uint2 pwa, pwb;
        pwa.x = cvt_pk_bf16(sa[s4][0], sa[s4][1]);
        pwa.y = cvt_pk_bf16(sa[s4][2], sa[s4][3]);
        pwb.x = cvt_pk_bf16(sb[s4][0], sb[s4][1]);
        pwb.y = cvt_pk_bf16(sb[s4][2], sb[s4][3]);
        *(uint2*)&Ps[w][0][offPw[s4]] = pwa;
        *(uint2*)&Ps[w][1][offPw[s4]] = pwb;
      }

      __builtin_amdgcn_s_setprio(1);
      #pragma unroll
      for (int c = 0; c < 2; ++c) {
        bf16x8 pa0 = *(const bf16x8*)&Ps[w][0][offPr[c]];
        bf16x8 pb0 = *(const bf16x8*)&Ps[w][1][offPr[c]];
        #pragma unroll
        for (int nf = 0; nf < 4; ++nf) {
          bf16x8 va = *(const bf16x8*)&Vs[buf][offVb[c][nf]];
          yacc[nf] = __builtin_amdgcn_mfma_f32_16x16x32_bf16(pa0, va, yacc[nf], 0, 0, 0);
          bf16x8 vb = *(const bf16x8*)&Vs[buf][offVb[c][nf] ^ 64];
          yacc[nf] = __builtin_amdgcn_mfma_f32_16x16x32_bf16(pb0, vb, yacc[nf], 0, 0, 0);
        }
      }
      __builtin_amdgcn_s_setprio(0);

      __syncthreads();
      buf ^= 1;
    }

    float srf = srun + __shfl_xor(srun, 16);
    srf += __shfl_xor(srf, 32);
    #pragma unroll
    for (int r = 0; r < 4; ++r) {
      float sv = __shfl(srf, g*4 + r);
      float inv = 1.f / sv;
      int qg = qrow + g*4 + r;
      #pragma unroll
      for (int nf = 0; nf < 4; ++nf) {
        int d = nf*16 + qi;
        yout[((size_t)bidx*SEQ + qg)*CH + h*HDIM + d] = f2b(yacc[nf][r] * inv);
      }
    }
  }
}

extern "C" void kernel_launch(void* const* d_in, const int* in_sizes, int n_in,
                              void* d_out, int out_size, void* d_ws, size_t ws_size,
                              hipStream_t stream) {
  (void)in_sizes; (void)n_in; (void)out_size; (void)ws_size;
  const float* x      = (const float*)d_in[0];
  const float* w_attn = (const float*)d_in[1];
  const float* b_attn = (const float*)d_in[2];
  const float* w_proj = (const float*)d_in[3];
  const float* b_proj = (const float*)d_in[4];

  char* ws = (char*)d_ws;
  const size_t MB = 1024*1024;
  u16* xb  = (u16*)(ws);             // 8 MB, reused as attention out y
  u16* wat = (u16*)(ws +  8*MB);     // 6 MB  w_attn^T [3072][1024]
  u16* wpt = (u16*)(ws + 14*MB);     // 2 MB  w_proj^T [1024][1024]
  u16* qb  = (u16*)(ws + 16*MB);     // 8 MB  [bh][t][64]
  u16* kb  = (u16*)(ws + 24*MB);     // 8 MB  [bh][t][64]
  u16* vtb = (u16*)(ws + 32*MB);     // 8 MB  [bh][64][t]

  csa_prep<<<6144, 256, 0, stream>>>(x, w_attn, w_proj, xb, wat, wpt);
  csa_gemm_qkv<<<dim3(16, 16), 512, 0, stream>>>(xb, wat, b_attn, qb, kb, vtb);
  csa_attn<<<dim3(32, 8), 512, 0, stream>>>(qb, kb, vtb, xb);
  csa_gemm_proj<<<dim3(8, 32), 256, 0, stream>>>(xb, wpt, b_proj, (float*)d_out);
}

// Round 19
// 99.282 us; speedup vs baseline: 1.0107x; 1.0107x over previous
//
#include <hip/hip_runtime.h>

typedef unsigned short u16;
typedef short bf16x8 __attribute__((ext_vector_type(8)));
typedef float f32x4 __attribute__((ext_vector_type(4)));

#define BATCH 2
#define SEQ   2048
#define CH    1024
#define NHEAD 16
#define HDIM  64
#define ROWS  (BATCH*SEQ)   // 4096

#define WAITV(N) asm volatile("s_waitcnt vmcnt(" #N ")" ::: "memory")

__device__ __forceinline__ u16 f2b(float f) {
  unsigned u = __builtin_bit_cast(unsigned, f);
  u += 0x7FFFu + ((u >> 16) & 1u);
  return (u16)(u >> 16);
}
__device__ __forceinline__ float b2f(u16 h) {
  unsigned u = ((unsigned)h) << 16;
  return __builtin_bit_cast(float, u);
}
__device__ __forceinline__ float exp2_fast(float x) {
  float r; asm("v_exp_f32 %0, %1" : "=v"(r) : "v"(x)); return r;
}
__device__ __forceinline__ unsigned cvt_pk_bf16(float a, float b) {
  unsigned r; asm("v_cvt_pk_bf16_f32 %0, %1, %2" : "=v"(r) : "v"(a), "v"(b)); return r;
}

__device__ __forceinline__ void gload_lds16(const void* g, void* l) {
  __builtin_amdgcn_global_load_lds(
      (const __attribute__((address_space(1))) unsigned int*)g,
      (__attribute__((address_space(3))) unsigned int*)l, 16, 0, 0);
}

// ---------- fused prep: x f32->bf16, both weight transposes (one launch) ----
__global__ void csa_prep(const float* __restrict__ x,
                         const float* __restrict__ wa, const float* __restrict__ wp,
                         u16* __restrict__ xb, u16* __restrict__ wat,
                         u16* __restrict__ wpt) {
  __shared__ float tile[32][33];
  const int b = blockIdx.x, t = threadIdx.x;
  if (b < 2048) {               // convert x: 524288 uint4-pairs
    int i = b * 256 + t;
    const float4* f4 = (const float4*)x;
    float4 v0 = f4[2*i], v1 = f4[2*i+1];
    ushort4 o0, o1;
    o0.x = f2b(v0.x); o0.y = f2b(v0.y); o0.z = f2b(v0.z); o0.w = f2b(v0.w);
    o1.x = f2b(v1.x); o1.y = f2b(v1.y); o1.z = f2b(v1.z); o1.w = f2b(v1.w);
    ((ushort4*)xb)[2*i]   = o0;
    ((ushort4*)xb)[2*i+1] = o1;
    return;
  }
  int bb = b - 2048;            // transpose: 4096 blocks (128 x 32)
  int bx = bb & 127, by = bb >> 7;
  const float* in; u16* out; int C;
  if (bx < 96) { in = wa; out = wat; C = 3*CH; }
  else         { in = wp; out = wpt; C = CH; bx -= 96; }
  const int R = CH;
  const int bxc = bx * 32, byc = by * 32;
  const int tx = t & 31, ty = t >> 5;
  #pragma unroll
  for (int j = 0; j < 4; ++j) {
    int r = byc + ty + j*8, c = bxc + tx;
    tile[ty + j*8][tx] = in[(size_t)r*C + c];
  }
  __syncthreads();
  #pragma unroll
  for (int j = 0; j < 4; ++j) {
    int oc = bxc + ty + j*8;
    int orr = byc + tx;
    out[(size_t)oc*R + orr] = f2b(tile[tx][ty + j*8]);
  }
}

// ---------- QKV GEMM: [4096][3072] = xb * wat^T + b -------------------------
// BM=256, BN=192, BK=64; 512 thr = 8 waves (2M x 4N); grid 16x16 = 1/CU.
// Counted-vmcnt pipeline (T4): A triple-buffered (2-iter latency cover),
// B double-buffered; raw s_barrier x2/iter, NO vmcnt(0) drain in main loop.
// T2 XOR swizzle on LDS tiles (read 16-way conflict -> 2-way free).
__global__ __launch_bounds__(512) void csa_gemm_qkv(
    const u16* __restrict__ A, const u16* __restrict__ Bt,
    const float* __restrict__ bias,
    u16* __restrict__ qbo, u16* __restrict__ kb, u16* __restrict__ vtb)
{
  __shared__ __align__(16) u16 As[3][256*64];   // 96 KB
  __shared__ __align__(16) u16 Bs[2][192*64];   // 48 KB
  const int t = threadIdx.x, lane = t & 63, w = t >> 6;
  const int wm = w >> 2, wn = w & 3, g = lane >> 4, qi = lane & 15;
  const int xq = (qi & 7) * 8;

  const int wgid = blockIdx.y * 16 + blockIdx.x;
  const int c8 = wgid & 7, inner = wgid >> 3;
  const int bm = (c8 >> 1) * 4 + (inner >> 3);
  const int bn = (c8 & 1) * 8 + (inner & 7);

  f32x4 acc[8][3] = {};

  const u16* Ab = A  + (size_t)(bm*256)*CH;
  const u16* Bb = Bt + (size_t)(bn*192)*CH;
  const int srow = t >> 3;                               // 0..63
  const int scolsw = ((t & 7) * 8) ^ ((srow & 7) * 8);   // pre-swizzled src col

#define QKV_STAGE_A(kt_, buf_) do { const size_t k_ = (size_t)(kt_)*64;            \
    gload_lds16(Ab + (size_t)(  0 + srow)*CH + k_ + scolsw, &As[buf_][      w*512]); \
    gload_lds16(Ab + (size_t)( 64 + srow)*CH + k_ + scolsw, &As[buf_][ 4096+w*512]); \
    gload_lds16(Ab + (size_t)(128 + srow)*CH + k_ + scolsw, &As[buf_][ 8192+w*512]); \
    gload_lds16(Ab + (size_t)(192 + srow)*CH + k_ + scolsw, &As[buf_][12288+w*512]); \
  } while (0)
#define QKV_STAGE_B(kt_, buf_) do { const size_t k_ = (size_t)(kt_)*64;            \
    gload_lds16(Bb + (size_t)(  0 + srow)*CH + k_ + scolsw, &Bs[buf_][      w*512]); \
    gload_lds16(Bb + (size_t)( 64 + srow)*CH + k_ + scolsw, &Bs[buf_][ 4096+w*512]); \
    gload_lds16(Bb + (size_t)(128 + srow)*CH + k_ + scolsw, &Bs[buf_][ 8192+w*512]); \
  } while (0)

  // prologue (FIFO order matters for vmcnt counting): A(0), B(0), A(1)
  QKV_STAGE_A(0, 0); QKV_STAGE_B(0, 0); QKV_STAGE_A(1, 1);

  int a3 = 0;                                  // kt % 3
  for (int kt = 0; kt < 16; ++kt) {
    if (kt < 15) QKV_STAGE_B(kt + 1, (kt + 1) & 1);
    if (kt < 14) { int ab = a3 + 2; if (ab >= 3) ab -= 3; QKV_STAGE_A(kt + 2, ab); }
    // drain exactly {A(kt), B(kt)}: keep A(kt+1)[4] + B(kt+1)[3] + A(kt+2)[4]
    if (kt < 14)       WAITV(11);
    else if (kt == 14) WAITV(7);
    else               WAITV(0);
    __builtin_amdgcn_s_barrier();              // all waves' tile-kt loads landed
    __builtin_amdgcn_sched_barrier(0);         // pin ds_reads after the barrier
    const u16* Ac = &As[a3][0];
    const u16* Bc = &Bs[kt & 1][0];
    #pragma unroll
    for (int kk = 0; kk < 2; ++kk) {
      bf16x8 af[8], bfr[3];
      #pragma unroll
      for (int m = 0; m < 8; ++m)
        af[m] = *(const bf16x8*)&Ac[(wm*128 + m*16 + qi)*64 + ((kk*32 + g*8) ^ xq)];
      #pragma unroll
      for (int n = 0; n < 3; ++n)
        bfr[n] = *(const bf16x8*)&Bc[(wn*48 + n*16 + qi)*64 + ((kk*32 + g*8) ^ xq)];
      #pragma unroll
      for (int m = 0; m < 8; ++m)
        #pragma unroll
        for (int n = 0; n < 3; ++n)
          acc[m][n] = __builtin_amdgcn_mfma_f32_16x16x32_bf16(af[m], bfr[n], acc[m][n], 0, 0, 0);
    }
    __builtin_amdgcn_s_barrier();              // reads done -> buffers reusable
    a3 = (a3 == 2) ? 0 : a3 + 1;
  }
#undef QKV_STAGE_A
#undef QKV_STAGE_B

  // epilogue: scatter to q/k [bh][t][64] and v^T [bh][64][t]
  #pragma unroll
  for (int m = 0; m < 8; ++m) {
    const int row0 = bm*256 + wm*128 + m*16 + g*4;
    const int bb = row0 >> 11;
    const int t0 = row0 & 2047;
    #pragma unroll
    for (int n = 0; n < 3; ++n) {
      const int col = bn*192 + wn*48 + n*16 + qi;
      const float bv = bias[col];
      const int which = col >> 10;      // 0=q 1=k 2=v
      const int cc = col & 1023;
      const int h = cc >> 6, d = cc & 63;
      const int bh = bb*16 + h;
      if (which == 2) {
        ushort4 pw;
        pw.x = f2b(acc[m][n][0] + bv);
        pw.y = f2b(acc[m][n][1] + bv);
        pw.z = f2b(acc[m][n][2] + bv);
        pw.w = f2b(acc[m][n][3] + bv);
        *(ushort4*)&vtb[((size_t)bh*HDIM + d)*SEQ + t0] = pw;
      } else {
        u16* dst = (which == 0) ? qbo : kb;
        #pragma unroll
        for (int r = 0; r < 4; ++r)
          dst[((size_t)bh*SEQ + t0 + r)*HDIM + d] = f2b(acc[m][n][r] + bv);
      }
    }
  }
}

// ---------- proj GEMM: out[4096][1024] f32 = y * wpt^T + b ------------------
// 128x128 tile, 256 thr (4 waves 2x2); same T4 counted-vmcnt + T2 swizzle.
__global__ __launch_bounds__(256) void csa_gemm_proj(
    const u16* __restrict__ A, const u16* __restrict__ Bt,
    const float* __restrict__ bias, float* __restrict__ out)
{
  __shared__ __align__(16) u16 As[3][128*64];   // 48 KB
  __shared__ __align__(16) u16 Bs[2][128*64];   // 32 KB
  const int t = threadIdx.x, lane = t & 63, w = t >> 6;
  const int wm = w >> 1, wn = w & 1, g = lane >> 4, qi = lane & 15;
  const int xq = (qi & 7) * 8;
  const int bm = blockIdx.y, bn = blockIdx.x;

  f32x4 acc[4][4] = {};

  const u16* Ab = A  + (size_t)(bm*128)*CH;
  const u16* Bb = Bt + (size_t)(bn*128)*CH;
  const int srow = t >> 3;                               // 0..31
  const int scolsw = ((t & 7) * 8) ^ ((srow & 7) * 8);

#define PRJ_STAGE(P_, base_, kt_, buf_) do { const size_t k_ = (size_t)(kt_)*64;      \
    gload_lds16(P_ + (size_t)( 0 + srow)*CH + k_ + scolsw, &base_[buf_][     w*512]); \
    gload_lds16(P_ + (size_t)(32 + srow)*CH + k_ + scolsw, &base_[buf_][2048+w*512]); \
    gload_lds16(P_ + (size_t)(64 + srow)*CH + k_ + scolsw, &base_[buf_][4096+w*512]); \
    gload_lds16(P_ + (size_t)(96 + srow)*CH + k_ + scolsw, &base_[buf_][6144+w*512]); \
  } while (0)

  PRJ_STAGE(Ab, As, 0, 0); PRJ_STAGE(Bb, Bs, 0, 0); PRJ_STAGE(Ab, As, 1, 1);

  int a3 = 0;
  for (int kt = 0; kt < 16; ++kt) {
    if (kt < 15) PRJ_STAGE(Bb, Bs, kt + 1, (kt + 1) & 1);
    if (kt < 14) { int ab = a3 + 2; if (ab >= 3) ab -= 3; PRJ_STAGE(Ab, As, kt + 2, ab); }
    if (kt < 14)       WAITV(12);   // keep A(kt+1)[4]+B(kt+1)[4]+A(kt+2)[4]
    else if (kt == 14) WAITV(8);
    else               WAITV(0);
    __builtin_amdgcn_s_barrier();
    __builtin_amdgcn_sched_barrier(0);
    const u16* Ac = &As[a3][0];
    const u16* Bc = &Bs[kt & 1][0];
    #pragma unroll
    for (int kk = 0; kk < 2; ++kk) {
      bf16x8 af[4], bfr[4];
      #pragma unroll
      for (int m = 0; m < 4; ++m)
        af[m] = *(const bf16x8*)&Ac[(wm*64 + m*16 + qi)*64 + ((kk*32 + g*8) ^ xq)];
      #pragma unroll
      for (int n = 0; n < 4; ++n)
        bfr[n] = *(const bf16x8*)&Bc[(wn*64 + n*16 + qi)*64 + ((kk*32 + g*8) ^ xq)];
      #pragma unroll
      for (int m = 0; m < 4; ++m)
        #pragma unroll
        for (int n = 0; n < 4; ++n)
          acc[m][n] = __builtin_amdgcn_mfma_f32_16x16x32_bf16(af[m], bfr[n], acc[m][n], 0, 0, 0);
    }
    __builtin_amdgcn_s_barrier();
    a3 = (a3 == 2) ? 0 : a3 + 1;
  }
#undef PRJ_STAGE

  #pragma unroll
  for (int m = 0; m < 4; ++m) {
    const int row0 = bm*128 + wm*64 + m*16 + g*4;
    #pragma unroll
    for (int n = 0; n < 4; ++n) {
      const int col = bn*128 + wn*64 + n*16 + qi;
      const float bv = bias[col];
      #pragma unroll
      for (int r = 0; r < 4; ++r)
        out[(size_t)(row0 + r)*CH + col] = acc[m][n][r] + bv;
    }
  }
}

// ---------- causal flash attention v5: KVBLK=128 (final) --------------------
// grid 32 x 8, 512 thr (8 waves x 16 q-rows), q-tile 128, pairs {p, 15-p}
// -> uniform 17 kt-iterations per block. Each iteration processes TWO 64-key
// sub-tiles (a/b) from one 128-key staged K/V tile. Double-buffered, single
// barrier per iteration. Swapped QK^T (mfma(K,Q)); per-lane-partial online
// softmax w/ defer-max; in-LDS per-wave P; branchless diagonal masking.
__global__ __launch_bounds__(512) void csa_attn(
    const u16* __restrict__ qb, const u16* __restrict__ kb,
    const u16* __restrict__ vtb, u16* __restrict__ yout)
{
  const int bh = blockIdx.x, pair = blockIdx.y;
  const int bidx = bh >> 4, h = bh & 15;
  const int t = threadIdx.x, lane = t & 63, w = t >> 6;   // w 0..7
  const int g = lane >> 4, qi = lane & 15;
  __shared__ __align__(16) u16 Ks[2][128*64];   // 32 KB
  __shared__ __align__(16) u16 Vs[2][64*128];   // 32 KB, V^T [d][key]
  __shared__ __align__(16) u16 Ps[8][2][16*64]; // 32 KB, per-wave P [sub][q][key]

  const size_t kvbase = (size_t)bh * SEQ * HDIM;
  const u16* kb_bh  = kb  + kvbase;
  const u16* vtb_bh = vtb + kvbase;

  const int krow_  = t >> 3;                                  // 0..63
  const int kcolsw = ((t & 7) * 8) ^ ((krow_ & 7) * 8);
  const int vd_    = t >> 4;                                  // 0..31
  const int vcolsw = ((t & 15) * 8) ^ ((vd_ & 15) * 8);

  int offKb[2][4], offVb[2][4], offPw[4], offPr[2];
  #pragma unroll
  for (int c = 0; c < 2; ++c) {
    offPr[c] = qi*64 + ((c*32 + g*8) ^ ((qi & 7) * 8));
    #pragma unroll
    for (int s4 = 0; s4 < 4; ++s4)
      offKb[c][s4] = (s4*16 + qi)*64 + ((c*32 + g*8) ^ ((qi & 7) * 8));
    #pragma unroll
    for (int nf = 0; nf < 4; ++nf)
      offVb[c][nf] = (nf*16 + qi)*128 + ((c*32 + g*8) ^ (qi * 8));
  }
  #pragma unroll
  for (int s4 = 0; s4 < 4; ++s4)
    offPw[s4] = qi*64 + ((s4*16 + g*4) ^ ((qi & 7) * 8));

  const float QSCALE = 0.18033688011112042f;   // 0.125 * log2(e)
  const int lqa = w*16 + qi;

  for (int half = 0; half < 2; ++half) {
    const int qt = half ? (15 - pair) : pair;
    const int qrow = qt*128 + w*16;
    const int ntile = qt + 1;

    bf16x8 qf[2];
    #pragma unroll
    for (int c = 0; c < 2; ++c) {
      qf[c] = *(const bf16x8*)&qb[(kvbase + (size_t)(qrow + qi)*HDIM) + c*32 + g*8];
      #pragma unroll
      for (int e = 0; e < 8; ++e)
        qf[c][e] = (short)f2b(b2f((u16)qf[c][e]) * QSCALE);
    }

    f32x4 yacc[4] = {};
    float mrun = -1e30f, srun = 0.f;

    __syncthreads();
    {
      const u16* kp = kb_bh;
      gload_lds16(kp + (size_t)krow_*64 + kcolsw,        &Ks[0][       w*512]);
      gload_lds16(kp + (size_t)(64 + krow_)*64 + kcolsw, &Ks[0][4096 + w*512]);
      const u16* vp = vtb_bh;
      gload_lds16(vp + (size_t)vd_*SEQ + vcolsw,         &Vs[0][       w*512]);
      gload_lds16(vp + (size_t)(32 + vd_)*SEQ + vcolsw,  &Vs[0][4096 + w*512]);
    }
    __syncthreads();

    int buf = 0;
    for (int kt = 0; kt < ntile; ++kt) {
      if (kt + 1 < ntile) {
        const u16* kp = kb_bh + (size_t)((kt + 1) * 128) * 64;
        gload_lds16(kp + (size_t)krow_*64 + kcolsw,        &Ks[buf^1][       w*512]);
        gload_lds16(kp + (size_t)(64 + krow_)*64 + kcolsw, &Ks[buf^1][4096 + w*512]);
        const u16* vp = vtb_bh + (kt + 1) * 128;
        gload_lds16(vp + (size_t)vd_*SEQ + vcolsw,         &Vs[buf^1][       w*512]);
        gload_lds16(vp + (size_t)(32 + vd_)*SEQ + vcolsw,  &Vs[buf^1][4096 + w*512]);
      }

      f32x4 sa[4] = {}, sb[4] = {};
      #pragma unroll
      for (int c = 0; c < 2; ++c)
        #pragma unroll
        for (int s4 = 0; s4 < 4; ++s4) {
          bf16x8 ka = *(const bf16x8*)&Ks[buf][offKb[c][s4]];
          sa[s4] = __builtin_amdgcn_mfma_f32_16x16x32_bf16(ka, qf[c], sa[s4], 0, 0, 0);
        }
      #pragma unroll
      for (int c = 0; c < 2; ++c)
        #pragma unroll
        for (int s4 = 0; s4 < 4; ++s4) {
          bf16x8 kbv = *(const bf16x8*)&Ks[buf][4096 + offKb[c][s4]];
          sb[s4] = __builtin_amdgcn_mfma_f32_16x16x32_bf16(kbv, qf[c], sb[s4], 0, 0, 0);
        }

      if (kt == ntile - 1) {
        #pragma unroll
        for (int s4 = 0; s4 < 4; ++s4)
          #pragma unroll
          for (int r = 0; r < 4; ++r) {
            const int lk = s4*16 + g*4 + r;
            if (lk > lqa)      sa[s4][r] = -3.0e38f;
            if (lk > lqa - 64) sb[s4][r] = -3.0e38f;
          }
      }

      float tmax = sa[0][0];
      #pragma unroll
      for (int s4 = 0; s4 < 4; ++s4)
        #pragma unroll
        for (int r = 0; r < 4; ++r) {
          tmax = fmaxf(tmax, sa[s4][r]);
          tmax = fmaxf(tmax, sb[s4][r]);
        }
      if (!__all(tmax - mrun <= 11.5f)) {
        float tmf = fmaxf(tmax, __shfl_xor(tmax, 16));
        tmf = fmaxf(tmf, __shfl_xor(tmf, 32));
        float mnew = fmaxf(mrun, tmf);
        float fac = exp2_fast(mrun - mnew);
        #pragma unroll
        for (int r = 0; r < 4; ++r) {
          float fr = __shfl(fac, g*4 + r);
          #pragma unroll
          for (int nf = 0; nf < 4; ++nf) yacc[nf][r] *= fr;
        }
        srun *= fac;
        mrun = mnew;
      }
      float tsum = 0.f;
      #pragma unroll
      for (int s4 = 0; s4 < 4; ++s4)
        #pragma unroll
        for (int r = 0; r < 4; ++r) {
          float pa = exp2_fast(sa[s4][r] - mrun);
          float pb = exp2_fast(sb[s4][r] - mrun);
          sa[s4][r] = pa; sb[s4][r] = pb;
          tsum += pa + pb;
        }
      srun += tsum;

      #pragma unroll
      for (int s4 = 0; s4 < 4; ++s4) {
        uint2 pwa, pwb;
        pwa.x = cvt_pk_bf16(sa[s4][0], sa[s4][1]);
        pwa.y = cvt_pk_bf16(sa[s4][2], sa[s4][3]);
        pwb.x = cvt_pk_bf16(sb[s4][0], sb[s4][1]);
        pwb.y = cvt_pk_bf16(sb[s4][2], sb[s4][3]);
        *(uint2*)&Ps[w][0][offPw[s4]] = pwa;
        *(uint2*)&Ps[w][1][offPw[s4]] = pwb;
      }

      #pragma unroll
      for (int c = 0; c < 2; ++c) {
        bf16x8 pa0 = *(const bf16x8*)&Ps[w][0][offPr[c]];
        bf16x8 pb0 = *(const bf16x8*)&Ps[w][1][offPr[c]];
        #pragma unroll
        for (int nf = 0; nf < 4; ++nf) {
          bf16x8 va = *(const bf16x8*)&Vs[buf][offVb[c][nf]];
          yacc[nf] = __builtin_amdgcn_mfma_f32_16x16x32_bf16(pa0, va, yacc[nf], 0, 0, 0);
          bf16x8 vb = *(const bf16x8*)&Vs[buf][offVb[c][nf] ^ 64];
          yacc[nf] = __builtin_amdgcn_mfma_f32_16x16x32_bf16(pb0, vb, yacc[nf], 0, 0, 0);
        }
      }

      __syncthreads();
      buf ^= 1;
    }

    float srf = srun + __shfl_xor(srun, 16);
    srf += __shfl_xor(srf, 32);
    #pragma unroll
    for (int r = 0; r < 4; ++r) {
      float sv = __shfl(srf, g*4 + r);
      float inv = 1.f / sv;
      int qg = qrow + g*4 + r;
      #pragma unroll
      for (int nf = 0; nf < 4; ++nf) {
        int d = nf*16 + qi;
        yout[((size_t)bidx*SEQ + qg)*CH + h*HDIM + d] = f2b(yacc[nf][r] * inv);
      }
    }
  }
}

extern "C" void kernel_launch(void* const* d_in, const int* in_sizes, int n_in,
                              void* d_out, int out_size, void* d_ws, size_t ws_size,
                              hipStream_t stream) {
  (void)in_sizes; (void)n_in; (void)out_size; (void)ws_size;
  const float* x      = (const float*)d_in[0];
  const float* w_attn = (const float*)d_in[1];
  const float* b_attn = (const float*)d_in[2];
  const float* w_proj = (const float*)d_in[3];
  const float* b_proj = (const float*)d_in[4];

  char* ws = (char*)d_ws;
  const size_t MB = 1024*1024;
  u16* xb  = (u16*)(ws);             // 8 MB, reused as attention out y
  u16* wat = (u16*)(ws +  8*MB);     // 6 MB  w_attn^T [3072][1024]
  u16* wpt = (u16*)(ws + 14*MB);     // 2 MB  w_proj^T [1024][1024]
  u16* qb  = (u16*)(ws + 16*MB);     // 8 MB  [bh][t][64]
  u16* kb  = (u16*)(ws + 24*MB);     // 8 MB  [bh][t][64]
  u16* vtb = (u16*)(ws + 32*MB);     // 8 MB  [bh][64][t]

  csa_prep<<<6144, 256, 0, stream>>>(x, w_attn, w_proj, xb, wat, wpt);
  csa_gemm_qkv<<<dim3(16, 16), 512, 0, stream>>>(xb, wat, b_attn, qb, kb, vtb);
  csa_attn<<<dim3(32, 8), 512, 0, stream>>>(qb, kb, vtb, xb);
  csa_gemm_proj<<<dim3(8, 32), 256, 0, stream>>>(xb, wpt, b_proj, (float*)d_out);
}

// Round 20
// 99.085 us; speedup vs baseline: 1.0127x; 1.0020x over previous
//
#include <hip/hip_runtime.h>

typedef unsigned short u16;
typedef short bf16x8 __attribute__((ext_vector_type(8)));
typedef float f32x4 __attribute__((ext_vector_type(4)));

#define BATCH 2
#define SEQ   2048
#define CH    1024
#define NHEAD 16
#define HDIM  64
#define ROWS  (BATCH*SEQ)   // 4096

#define WAITV(N) asm volatile("s_waitcnt vmcnt(" #N ")" ::: "memory")

__device__ __forceinline__ u16 f2b(float f) {
  unsigned u = __builtin_bit_cast(unsigned, f);
  u += 0x7FFFu + ((u >> 16) & 1u);
  return (u16)(u >> 16);
}
__device__ __forceinline__ float b2f(u16 h) {
  unsigned u = ((unsigned)h) << 16;
  return __builtin_bit_cast(float, u);
}
__device__ __forceinline__ float exp2_fast(float x) {
  float r; asm("v_exp_f32 %0, %1" : "=v"(r) : "v"(x)); return r;
}
__device__ __forceinline__ unsigned cvt_pk_bf16(float a, float b) {
  unsigned r; asm("v_cvt_pk_bf16_f32 %0, %1, %2" : "=v"(r) : "v"(a), "v"(b)); return r;
}

__device__ __forceinline__ void gload_lds16(const void* g, void* l) {
  __builtin_amdgcn_global_load_lds(
      (const __attribute__((address_space(1))) unsigned int*)g,
      (__attribute__((address_space(3))) unsigned int*)l, 16, 0, 0);
}

// ---------- fused prep: x f32->bf16, both weight transposes (one launch) ----
__global__ void csa_prep(const float* __restrict__ x,
                         const float* __restrict__ wa, const float* __restrict__ wp,
                         u16* __restrict__ xb, u16* __restrict__ wat,
                         u16* __restrict__ wpt) {
  __shared__ float tile[32][33];
  const int b = blockIdx.x, t = threadIdx.x;
  if (b < 2048) {               // convert x: 524288 uint4-pairs
    int i = b * 256 + t;
    const float4* f4 = (const float4*)x;
    float4 v0 = f4[2*i], v1 = f4[2*i+1];
    ushort4 o0, o1;
    o0.x = f2b(v0.x); o0.y = f2b(v0.y); o0.z = f2b(v0.z); o0.w = f2b(v0.w);
    o1.x = f2b(v1.x); o1.y = f2b(v1.y); o1.z = f2b(v1.z); o1.w = f2b(v1.w);
    ((ushort4*)xb)[2*i]   = o0;
    ((ushort4*)xb)[2*i+1] = o1;
    return;
  }
  int bb = b - 2048;            // transpose: 4096 blocks (128 x 32)
  int bx = bb & 127, by = bb >> 7;
  const float* in; u16* out; int C;
  if (bx < 96) { in = wa; out = wat; C = 3*CH; }
  else         { in = wp; out = wpt; C = CH; bx -= 96; }
  const int R = CH;
  const int bxc = bx * 32, byc = by * 32;
  const int tx = t & 31, ty = t >> 5;
  #pragma unroll
  for (int j = 0; j < 4; ++j) {
    int r = byc + ty + j*8, c = bxc + tx;
    tile[ty + j*8][tx] = in[(size_t)r*C + c];
  }
  __syncthreads();
  #pragma unroll
  for (int j = 0; j < 4; ++j) {
    int oc = bxc + ty + j*8;
    int orr = byc + tx;
    out[(size_t)oc*R + orr] = f2b(tile[tx][ty + j*8]);
  }
}

// ---------- QKV GEMM: [4096][3072] = xb * wat^T + b -------------------------
// BM=256, BN=192, BK=64; 512 thr = 8 waves (2M x 4N); grid 16x16 = 1/CU.
// Counted-vmcnt pipeline (T4): A triple-buffered (2-iter latency cover),
// B double-buffered; raw s_barrier x2/iter, NO vmcnt(0) drain in main loop.
// T2 XOR swizzle on LDS tiles (read 16-way conflict -> 2-way free).
__global__ __launch_bounds__(512) void csa_gemm_qkv(
    const u16* __restrict__ A, const u16* __restrict__ Bt,
    const float* __restrict__ bias,
    u16* __restrict__ qbo, u16* __restrict__ kb, u16* __restrict__ vtb)
{
  __shared__ __align__(16) u16 As[3][256*64];   // 96 KB
  __shared__ __align__(16) u16 Bs[2][192*64];   // 48 KB
  const int t = threadIdx.x, lane = t & 63, w = t >> 6;
  const int wm = w >> 2, wn = w & 3, g = lane >> 4, qi = lane & 15;
  const int xq = (qi & 7) * 8;

  const int wgid = blockIdx.y * 16 + blockIdx.x;
  const int c8 = wgid & 7, inner = wgid >> 3;
  const int bm = (c8 >> 1) * 4 + (inner >> 3);
  const int bn = (c8 & 1) * 8 + (inner & 7);

  f32x4 acc[8][3] = {};

  const u16* Ab = A  + (size_t)(bm*256)*CH;
  const u16* Bb = Bt + (size_t)(bn*192)*CH;
  const int srow = t >> 3;                               // 0..63
  const int scolsw = ((t & 7) * 8) ^ ((srow & 7) * 8);   // pre-swizzled src col

#define QKV_STAGE_A(kt_, buf_) do { const size_t k_ = (size_t)(kt_)*64;            \
    gload_lds16(Ab + (size_t)(  0 + srow)*CH + k_ + scolsw, &As[buf_][      w*512]); \
    gload_lds16(Ab + (size_t)( 64 + srow)*CH + k_ + scolsw, &As[buf_][ 4096+w*512]); \
    gload_lds16(Ab + (size_t)(128 + srow)*CH + k_ + scolsw, &As[buf_][ 8192+w*512]); \
    gload_lds16(Ab + (size_t)(192 + srow)*CH + k_ + scolsw, &As[buf_][12288+w*512]); \
  } while (0)
#define QKV_STAGE_B(kt_, buf_) do { const size_t k_ = (size_t)(kt_)*64;            \
    gload_lds16(Bb + (size_t)(  0 + srow)*CH + k_ + scolsw, &Bs[buf_][      w*512]); \
    gload_lds16(Bb + (size_t)( 64 + srow)*CH + k_ + scolsw, &Bs[buf_][ 4096+w*512]); \
    gload_lds16(Bb + (size_t)(128 + srow)*CH + k_ + scolsw, &Bs[buf_][ 8192+w*512]); \
  } while (0)

  // prologue (FIFO order matters for vmcnt counting): A(0), B(0), A(1)
  QKV_STAGE_A(0, 0); QKV_STAGE_B(0, 0); QKV_STAGE_A(1, 1);

  int a3 = 0;                                  // kt % 3
  for (int kt = 0; kt < 16; ++kt) {
    if (kt < 15) QKV_STAGE_B(kt + 1, (kt + 1) & 1);
    if (kt < 14) { int ab = a3 + 2; if (ab >= 3) ab -= 3; QKV_STAGE_A(kt + 2, ab); }
    // drain exactly {A(kt), B(kt)}: keep A(kt+1)[4] + B(kt+1)[3] + A(kt+2)[4]
    if (kt < 14)       WAITV(11);
    else if (kt == 14) WAITV(7);
    else               WAITV(0);
    __builtin_amdgcn_s_barrier();              // all waves' tile-kt loads landed
    __builtin_amdgcn_sched_barrier(0);         // pin ds_reads after the barrier
    const u16* Ac = &As[a3][0];
    const u16* Bc = &Bs[kt & 1][0];
    #pragma unroll
    for (int kk = 0; kk < 2; ++kk) {
      bf16x8 af[8], bfr[3];
      #pragma unroll
      for (int m = 0; m < 8; ++m)
        af[m] = *(const bf16x8*)&Ac[(wm*128 + m*16 + qi)*64 + ((kk*32 + g*8) ^ xq)];
      #pragma unroll
      for (int n = 0; n < 3; ++n)
        bfr[n] = *(const bf16x8*)&Bc[(wn*48 + n*16 + qi)*64 + ((kk*32 + g*8) ^ xq)];
      #pragma unroll
      for (int m = 0; m < 8; ++m)
        #pragma unroll
        for (int n = 0; n < 3; ++n)
          acc[m][n] = __builtin_amdgcn_mfma_f32_16x16x32_bf16(af[m], bfr[n], acc[m][n], 0, 0, 0);
    }
    __builtin_amdgcn_s_barrier();              // reads done -> buffers reusable
    a3 = (a3 == 2) ? 0 : a3 + 1;
  }
#undef QKV_STAGE_A
#undef QKV_STAGE_B

  // epilogue: scatter to q/k [bh][t][64] and v^T [bh][64][t]
  #pragma unroll
  for (int m = 0; m < 8; ++m) {
    const int row0 = bm*256 + wm*128 + m*16 + g*4;
    const int bb = row0 >> 11;
    const int t0 = row0 & 2047;
    #pragma unroll
    for (int n = 0; n < 3; ++n) {
      const int col = bn*192 + wn*48 + n*16 + qi;
      const float bv = bias[col];
      const int which = col >> 10;      // 0=q 1=k 2=v
      const int cc = col & 1023;
      const int h = cc >> 6, d = cc & 63;
      const int bh = bb*16 + h;
      if (which == 2) {
        ushort4 pw;
        pw.x = f2b(acc[m][n][0] + bv);
        pw.y = f2b(acc[m][n][1] + bv);
        pw.z = f2b(acc[m][n][2] + bv);
        pw.w = f2b(acc[m][n][3] + bv);
        *(ushort4*)&vtb[((size_t)bh*HDIM + d)*SEQ + t0] = pw;
      } else {
        u16* dst = (which == 0) ? qbo : kb;
        #pragma unroll
        for (int r = 0; r < 4; ++r)
          dst[((size_t)bh*SEQ + t0 + r)*HDIM + d] = f2b(acc[m][n][r] + bv);
      }
    }
  }
}

// ---------- proj GEMM: out[4096][1024] f32 = y * wpt^T + b ------------------
// 128x128 tile, 256 thr (4 waves 2x2); same T4 counted-vmcnt + T2 swizzle.
__global__ __launch_bounds__(256) void csa_gemm_proj(
    const u16* __restrict__ A, const u16* __restrict__ Bt,
    const float* __restrict__ bias, float* __restrict__ out)
{
  __shared__ __align__(16) u16 As[3][128*64];   // 48 KB
  __shared__ __align__(16) u16 Bs[2][128*64];   // 32 KB
  const int t = threadIdx.x, lane = t & 63, w = t >> 6;
  const int wm = w >> 1, wn = w & 1, g = lane >> 4, qi = lane & 15;
  const int xq = (qi & 7) * 8;
  const int bm = blockIdx.y, bn = blockIdx.x;

  f32x4 acc[4][4] = {};

  const u16* Ab = A  + (size_t)(bm*128)*CH;
  const u16* Bb = Bt + (size_t)(bn*128)*CH;
  const int srow = t >> 3;                               // 0..31
  const int scolsw = ((t & 7) * 8) ^ ((srow & 7) * 8);

#define PRJ_STAGE(P_, base_, kt_, buf_) do { const size_t k_ = (size_t)(kt_)*64;      \
    gload_lds16(P_ + (size_t)( 0 + srow)*CH + k_ + scolsw, &base_[buf_][     w*512]); \
    gload_lds16(P_ + (size_t)(32 + srow)*CH + k_ + scolsw, &base_[buf_][2048+w*512]); \
    gload_lds16(P_ + (size_t)(64 + srow)*CH + k_ + scolsw, &base_[buf_][4096+w*512]); \
    gload_lds16(P_ + (size_t)(96 + srow)*CH + k_ + scolsw, &base_[buf_][6144+w*512]); \
  } while (0)

  PRJ_STAGE(Ab, As, 0, 0); PRJ_STAGE(Bb, Bs, 0, 0); PRJ_STAGE(Ab, As, 1, 1);

  int a3 = 0;
  for (int kt = 0; kt < 16; ++kt) {
    if (kt < 15) PRJ_STAGE(Bb, Bs, kt + 1, (kt + 1) & 1);
    if (kt < 14) { int ab = a3 + 2; if (ab >= 3) ab -= 3; PRJ_STAGE(Ab, As, kt + 2, ab); }
    if (kt < 14)       WAITV(12);   // keep A(kt+1)[4]+B(kt+1)[4]+A(kt+2)[4]
    else if (kt == 14) WAITV(8);
    else               WAITV(0);
    __builtin_amdgcn_s_barrier();
    __builtin_amdgcn_sched_barrier(0);
    const u16* Ac = &As[a3][0];
    const u16* Bc = &Bs[kt & 1][0];
    #pragma unroll
    for (int kk = 0; kk < 2; ++kk) {
      bf16x8 af[4], bfr[4];
      #pragma unroll
      for (int m = 0; m < 4; ++m)
        af[m] = *(const bf16x8*)&Ac[(wm*64 + m*16 + qi)*64 + ((kk*32 + g*8) ^ xq)];
      #pragma unroll
      for (int n = 0; n < 4; ++n)
        bfr[n] = *(const bf16x8*)&Bc[(wn*64 + n*16 + qi)*64 + ((kk*32 + g*8) ^ xq)];
      #pragma unroll
      for (int m = 0; m < 4; ++m)
        #pragma unroll
        for (int n = 0; n < 4; ++n)
          acc[m][n] = __builtin_amdgcn_mfma_f32_16x16x32_bf16(af[m], bfr[n], acc[m][n], 0, 0, 0);
    }
    __builtin_amdgcn_s_barrier();
    a3 = (a3 == 2) ? 0 : a3 + 1;
  }
#undef PRJ_STAGE

  #pragma unroll
  for (int m = 0; m < 4; ++m) {
    const int row0 = bm*128 + wm*64 + m*16 + g*4;
    #pragma unroll
    for (int n = 0; n < 4; ++n) {
      const int col = bn*128 + wn*64 + n*16 + qi;
      const float bv = bias[col];
      #pragma unroll
      for (int r = 0; r < 4; ++r)
        out[(size_t)(row0 + r)*CH + col] = acc[m][n][r] + bv;
    }
  }
}

// ---------- causal flash attention v5: KVBLK=128 (final) --------------------
// grid 32 x 8, 512 thr (8 waves x 16 q-rows), q-tile 128, pairs {p, 15-p}
// -> uniform 17 kt-iterations per block. Each iteration processes TWO 64-key
// sub-tiles (a/b) from one 128-key staged K/V tile. Double-buffered, single
// barrier per iteration. Swapped QK^T (mfma(K,Q)); per-lane-partial online
// softmax w/ defer-max; in-LDS per-wave P; branchless diagonal masking.
__global__ __launch_bounds__(512) void csa_attn(
    const u16* __restrict__ qb, const u16* __restrict__ kb,
    const u16* __restrict__ vtb, u16* __restrict__ yout)
{
  const int bh = blockIdx.x, pair = blockIdx.y;
  const int bidx = bh >> 4, h = bh & 15;
  const int t = threadIdx.x, lane = t & 63, w = t >> 6;   // w 0..7
  const int g = lane >> 4, qi = lane & 15;
  __shared__ __align__(16) u16 Ks[2][128*64];   // 32 KB
  __shared__ __align__(16) u16 Vs[2][64*128];   // 32 KB, V^T [d][key]
  __shared__ __align__(16) u16 Ps[8][2][16*64]; // 32 KB, per-wave P [sub][q][key]

  const size_t kvbase = (size_t)bh * SEQ * HDIM;
  const u16* kb_bh  = kb  + kvbase;
  const u16* vtb_bh = vtb + kvbase;

  const int krow_  = t >> 3;                                  // 0..63
  const int kcolsw = ((t & 7) * 8) ^ ((krow_ & 7) * 8);
  const int vd_    = t >> 4;                                  // 0..31
  const int vcolsw = ((t & 15) * 8) ^ ((vd_ & 15) * 8);

  int offKb[2][4], offVb[2][4], offPw[4], offPr[2];
  #pragma unroll
  for (int c = 0; c < 2; ++c) {
    offPr[c] = qi*64 + ((c*32 + g*8) ^ ((qi & 7) * 8));
    #pragma unroll
    for (int s4 = 0; s4 < 4; ++s4)
      offKb[c][s4] = (s4*16 + qi)*64 + ((c*32 + g*8) ^ ((qi & 7) * 8));
    #pragma unroll
    for (int nf = 0; nf < 4; ++nf)
      offVb[c][nf] = (nf*16 + qi)*128 + ((c*32 + g*8) ^ (qi * 8));
  }
  #pragma unroll
  for (int s4 = 0; s4 < 4; ++s4)
    offPw[s4] = qi*64 + ((s4*16 + g*4) ^ ((qi & 7) * 8));

  const float QSCALE = 0.18033688011112042f;   // 0.125 * log2(e)
  const int lqa = w*16 + qi;

  for (int half = 0; half < 2; ++half) {
    const int qt = half ? (15 - pair) : pair;
    const int qrow = qt*128 + w*16;
    const int ntile = qt + 1;

    bf16x8 qf[2];
    #pragma unroll
    for (int c = 0; c < 2; ++c) {
      qf[c] = *(const bf16x8*)&qb[(kvbase + (size_t)(qrow + qi)*HDIM) + c*32 + g*8];
      #pragma unroll
      for (int e = 0; e < 8; ++e)
        qf[c][e] = (short)f2b(b2f((u16)qf[c][e]) * QSCALE);
    }

    f32x4 yacc[4] = {};
    float mrun = -1e30f, srun = 0.f;

    __syncthreads();
    {
      const u16* kp = kb_bh;
      gload_lds16(kp + (size_t)krow_*64 + kcolsw,        &Ks[0][       w*512]);
      gload_lds16(kp + (size_t)(64 + krow_)*64 + kcolsw, &Ks[0][4096 + w*512]);
      const u16* vp = vtb_bh;
      gload_lds16(vp + (size_t)vd_*SEQ + vcolsw,         &Vs[0][       w*512]);
      gload_lds16(vp + (size_t)(32 + vd_)*SEQ + vcolsw,  &Vs[0][4096 + w*512]);
    }
    __syncthreads();

    int buf = 0;
    for (int kt = 0; kt < ntile; ++kt) {
      if (kt + 1 < ntile) {
        const u16* kp = kb_bh + (size_t)((kt + 1) * 128) * 64;
        gload_lds16(kp + (size_t)krow_*64 + kcolsw,        &Ks[buf^1][       w*512]);
        gload_lds16(kp + (size_t)(64 + krow_)*64 + kcolsw, &Ks[buf^1][4096 + w*512]);
        const u16* vp = vtb_bh + (kt + 1) * 128;
        gload_lds16(vp + (size_t)vd_*SEQ + vcolsw,         &Vs[buf^1][       w*512]);
        gload_lds16(vp + (size_t)(32 + vd_)*SEQ + vcolsw,  &Vs[buf^1][4096 + w*512]);
      }

      f32x4 sa[4] = {}, sb[4] = {};
      #pragma unroll
      for (int c = 0; c < 2; ++c)
        #pragma unroll
        for (int s4 = 0; s4 < 4; ++s4) {
          bf16x8 ka = *(const bf16x8*)&Ks[buf][offKb[c][s4]];
          sa[s4] = __builtin_amdgcn_mfma_f32_16x16x32_bf16(ka, qf[c], sa[s4], 0, 0, 0);
        }
      #pragma unroll
      for (int c = 0; c < 2; ++c)
        #pragma unroll
        for (int s4 = 0; s4 < 4; ++s4) {
          bf16x8 kbv = *(const bf16x8*)&Ks[buf][4096 + offKb[c][s4]];
          sb[s4] = __builtin_amdgcn_mfma_f32_16x16x32_bf16(kbv, qf[c], sb[s4], 0, 0, 0);
        }

      if (kt == ntile - 1) {
        #pragma unroll
        for (int s4 = 0; s4 < 4; ++s4)
          #pragma unroll
          for (int r = 0; r < 4; ++r) {
            const int lk = s4*16 + g*4 + r;
            if (lk > lqa)      sa[s4][r] = -3.0e38f;
            if (lk > lqa - 64) sb[s4][r] = -3.0e38f;
          }
      }

      float tmax = sa[0][0];
      #pragma unroll
      for (int s4 = 0; s4 < 4; ++s4)
        #pragma unroll
        for (int r = 0; r < 4; ++r) {
          tmax = fmaxf(tmax, sa[s4][r]);
          tmax = fmaxf(tmax, sb[s4][r]);
        }
      if (!__all(tmax - mrun <= 11.5f)) {
        float tmf = fmaxf(tmax, __shfl_xor(tmax, 16));
        tmf = fmaxf(tmf, __shfl_xor(tmf, 32));
        float mnew = fmaxf(mrun, tmf);
        float fac = exp2_fast(mrun - mnew);
        #pragma unroll
        for (int r = 0; r < 4; ++r) {
          float fr = __shfl(fac, g*4 + r);
          #pragma unroll
          for (int nf = 0; nf < 4; ++nf) yacc[nf][r] *= fr;
        }
        srun *= fac;
        mrun = mnew;
      }
      float tsum = 0.f;
      #pragma unroll
      for (int s4 = 0; s4 < 4; ++s4)
        #pragma unroll
        for (int r = 0; r < 4; ++r) {
          float pa = exp2_fast(sa[s4][r] - mrun);
          float pb = exp2_fast(sb[s4][r] - mrun);
          sa[s4][r] = pa; sb[s4][r] = pb;
          tsum += pa + pb;
        }
      srun += tsum;

      #pragma unroll
      for (int s4 = 0; s4 < 4; ++s4) {
        uint2 pwa, pwb;
        pwa.x = cvt_pk_bf16(sa[s4][0], sa[s4][1]);
        pwa.y = cvt_pk_bf16(sa[s4][2], sa[s4][3]);
        pwb.x = cvt_pk_bf16(sb[s4][0], sb[s4][1]);
        pwb.y = cvt_pk_bf16(sb[s4][2], sb[s4][3]);
        *(uint2*)&Ps[w][0][offPw[s4]] = pwa;
        *(uint2*)&Ps[w][1][offPw[s4]] = pwb;
      }

      #pragma unroll
      for (int c = 0; c < 2; ++c) {
        bf16x8 pa0 = *(const bf16x8*)&Ps[w][0][offPr[c]];
        bf16x8 pb0 = *(const bf16x8*)&Ps[w][1][offPr[c]];
        #pragma unroll
        for (int nf = 0; nf < 4; ++nf) {
          bf16x8 va = *(const bf16x8*)&Vs[buf][offVb[c][nf]];
          yacc[nf] = __builtin_amdgcn_mfma_f32_16x16x32_bf16(pa0, va, yacc[nf], 0, 0, 0);
          bf16x8 vb = *(const bf16x8*)&Vs[buf][offVb[c][nf] ^ 64];
          yacc[nf] = __builtin_amdgcn_mfma_f32_16x16x32_bf16(pb0, vb, yacc[nf], 0, 0, 0);
        }
      }

      __syncthreads();
      buf ^= 1;
    }

    float srf = srun + __shfl_xor(srun, 16);
    srf += __shfl_xor(srf, 32);
    #pragma unroll
    for (int r = 0; r < 4; ++r) {
      float sv = __shfl(srf, g*4 + r);
      float inv = 1.f / sv;
      int qg = qrow + g*4 + r;
      #pragma unroll
      for (int nf = 0; nf < 4; ++nf) {
        int d = nf*16 + qi;
        yout[((size_t)bidx*SEQ + qg)*CH + h*HDIM + d] = f2b(yacc[nf][r] * inv);
      }
    }
  }
}

extern "C" void kernel_launch(void* const* d_in, const int* in_sizes, int n_in,
                              void* d_out, int out_size, void* d_ws, size_t ws_size,
                              hipStream_t stream) {
  (void)in_sizes; (void)n_in; (void)out_size; (void)ws_size;
  const float* x      = (const float*)d_in[0];
  const float* w_attn = (const float*)d_in[1];
  const float* b_attn = (const float*)d_in[2];
  const float* w_proj = (const float*)d_in[3];
  const float* b_proj = (const float*)d_in[4];

  char* ws = (char*)d_ws;
  const size_t MB = 1024*1024;
  u16* xb  = (u16*)(ws);             // 8 MB, reused as attention out y
  u16* wat = (u16*)(ws +  8*MB);     // 6 MB  w_attn^T [3072][1024]
  u16* wpt = (u16*)(ws + 14*MB);     // 2 MB  w_proj^T [1024][1024]
  u16* qb  = (u16*)(ws + 16*MB);     // 8 MB  [bh][t][64]
  u16* kb  = (u16*)(ws + 24*MB);     // 8 MB  [bh][t][64]
  u16* vtb = (u16*)(ws + 32*MB);     // 8 MB  [bh][64][t]

  csa_prep<<<6144, 256, 0, stream>>>(x, w_attn, w_proj, xb, wat, wpt);
  csa_gemm_qkv<<<dim3(16, 16), 512, 0, stream>>>(xb, wat, b_attn, qb, kb, vtb);
  csa_attn<<<dim3(32, 8), 512, 0, stream>>>(qb, kb, vtb, xb);
  csa_gemm_proj<<<dim3(8, 32), 256, 0, stream>>>(xb, wpt, b_proj, (float*)d_out);
}